// Round 1
// baseline (1610.617 us; speedup 1.0000x reference)
//
#include <hip/hip_runtime.h>
#include <math.h>

#define B_ 4
#define S_ 4096
#define D_ 768
#define U_ 64

#define TQ 32
#define TK 64
#define SP 68   // padded LDS stride (floats): breaks stride-64 bank conflicts, keeps 16B alignment

// ---------------- kernel 1: decode mask (auto-detect bool8 vs int32) ----------------
__global__ __launch_bounds__(256) void decode_mask_k(const unsigned char* __restrict__ mraw,
                                                     float* __restrict__ maskf) {
    // Detection: if the buffer is int32 (values 0/1), every byte at offset %4 != 0 is zero.
    // If it's 1-byte bool, ~half of 768 tested off-word bytes are 1 -> detected.
    int base = threadIdx.x * 4;  // scan first 1024 bytes (safe for both layouts)
    int bad = (mraw[base + 1] | mraw[base + 2] | mraw[base + 3]) != 0;
    int isbyte = __syncthreads_or(bad);
    int i = blockIdx.x * 256 + threadIdx.x;
    if (i < B_ * S_) {
        int v = isbyte ? (int)mraw[i] : ((const int*)mraw)[i];
        maskf[i] = (v != 0) ? 1.0f : 0.0f;
    }
}

// ---------------- kernel 2: q/k projection (no masking needed; see analysis) ----------------
__global__ __launch_bounds__(256) void proj_qk_k(const float* __restrict__ x,
                                                 const float* __restrict__ Wq,
                                                 const float* __restrict__ Wk,
                                                 float* __restrict__ qout,
                                                 float* __restrict__ kout) {
    __shared__ float xs[16][D_];   // 48KB
    const int rbase = blockIdx.x * 16;   // global row index into [B*S]
    const float4* xsrc = (const float4*)(x + (size_t)rbase * D_);
    float4* xdst = (float4*)&xs[0][0];
    for (int i = threadIdx.x; i < 16 * D_ / 4; i += 256) xdst[i] = xsrc[i];
    __syncthreads();

    const int c  = threadIdx.x & 127;   // 0..63 -> q col, 64..127 -> k col (wave-uniform W choice)
    const int rg = threadIdx.x >> 7;    // row group 0/1
    const float* __restrict__ W = (c < 64) ? Wq : Wk;
    const int u = c & 63;

    float acc[8] = {0.f,0.f,0.f,0.f,0.f,0.f,0.f,0.f};
    #pragma unroll 4
    for (int d = 0; d < D_; ++d) {
        float w = W[d * U_ + u];
        #pragma unroll
        for (int r = 0; r < 8; ++r) acc[r] = fmaf(xs[rg * 8 + r][d], w, acc[r]);
    }
    float* __restrict__ dst = (c < 64) ? qout : kout;
    #pragma unroll
    for (int r = 0; r < 8; ++r) dst[(size_t)(rbase + rg * 8 + r) * U_ + u] = acc[r];
}

// ---------------- kernel 3: flash attention, fp32 vector ----------------
#define FMA4(a, p, v) { (a).x = fmaf((p),(v).x,(a).x); (a).y = fmaf((p),(v).y,(a).y); \
                        (a).z = fmaf((p),(v).z,(a).z); (a).w = fmaf((p),(v).w,(a).w); }

__global__ __launch_bounds__(256) void attn_k(const float* __restrict__ x,
                                              const float* __restrict__ qg,
                                              const float* __restrict__ kg,
                                              const float* __restrict__ maskf,
                                              float* __restrict__ out) {
    __shared__ float q_lds[TQ][SP];
    __shared__ float k_lds[TK][SP];
    __shared__ float s_lds[TQ][SP];   // logits, then reused for p (rows are wave-private)

    const int b     = blockIdx.x >> 7;           // S/TQ = 128 tiles per batch
    const int qbase = (blockIdx.x & 127) * TQ;
    const int tid   = threadIdx.x;
    const int wave  = tid >> 6;
    const int lane  = tid & 63;
    const int i_row = tid >> 3;   // phase-1 row 0..31  (== wave*8 + (lane>>3): wave-private rows)
    const int jg    = tid & 7;    // phase-1 j-interleave

    // load Q tile (fp32, 32x64)
    {
        const float* qsrc = qg + ((size_t)b * S_ + qbase) * U_;
        for (int i = tid; i < TQ * U_; i += 256) q_lds[i >> 6][i & 63] = qsrc[i];
    }

    float4 acc[8][3];
    #pragma unroll
    for (int r = 0; r < 8; ++r) {
        #pragma unroll
        for (int c = 0; c < 3; ++c) acc[r][c] = make_float4(0.f, 0.f, 0.f, 0.f);
    }
    float m_run[8], l_run[8];
    #pragma unroll
    for (int r = 0; r < 8; ++r) { m_run[r] = -INFINITY; l_run[r] = 0.f; }

    const float* __restrict__ mrow = maskf + (size_t)b * S_;

    for (int kt = 0; kt < S_ / TK; ++kt) {
        const int kbase = kt * TK;

        // stage K tile 64x64 (coalesced float4)
        {
            const float4* ksrc = (const float4*)(kg + ((size_t)b * S_ + kbase) * U_);
            for (int i = tid; i < TK * U_ / 4; i += 256)
                *(float4*)&k_lds[i >> 4][(i & 15) * 4] = ksrc[i];
        }
        __syncthreads();

        // phase 1: s[i][j] = q_i . k_j * 0.125, key-masked -> -inf
        {
            float sa[8] = {0.f,0.f,0.f,0.f,0.f,0.f,0.f,0.f};
            #pragma unroll
            for (int kk = 0; kk < U_; kk += 4) {
                float4 qv = *(const float4*)&q_lds[i_row][kk];
                #pragma unroll
                for (int jj = 0; jj < 8; ++jj) {
                    float4 kv = *(const float4*)&k_lds[jg + 8 * jj][kk];
                    sa[jj] += qv.x * kv.x + qv.y * kv.y + qv.z * kv.z + qv.w * kv.w;
                }
            }
            #pragma unroll
            for (int jj = 0; jj < 8; ++jj) {
                int j = jg + 8 * jj;
                float mk = mrow[kbase + j];
                s_lds[i_row][j] = (mk > 0.f) ? sa[jj] * 0.125f : -INFINITY;
            }
        }
        __syncthreads();   // protects k_lds: all phase-1 reads done before next stage overwrites

        // phase 2: online softmax for this wave's 8 rows (s rows are wave-private)
        #pragma unroll
        for (int r = 0; r < 8; ++r) {
            const int row = wave * 8 + r;
            float sv = s_lds[row][lane];
            float mx = sv;
            #pragma unroll
            for (int off = 32; off >= 1; off >>= 1) mx = fmaxf(mx, __shfl_xor(mx, off));
            float mn = fmaxf(m_run[r], mx);
            float p, scale;
            if (mn == -INFINITY) {         // everything masked so far for this row
                p = 0.f; scale = 1.f;
            } else {
                p = __expf(sv - mn);              // sv = -inf  -> 0
                scale = __expf(m_run[r] - mn);    // m_run = -inf -> 0 (acc is 0 anyway)
                m_run[r] = mn;
            }
            float ps = p;
            #pragma unroll
            for (int off = 32; off >= 1; off >>= 1) ps += __shfl_xor(ps, off);
            l_run[r] = l_run[r] * scale + ps;
            #pragma unroll
            for (int c = 0; c < 3; ++c) {
                acc[r][c].x *= scale; acc[r][c].y *= scale;
                acc[r][c].z *= scale; acc[r][c].w *= scale;
            }
            s_lds[row][lane] = p;   // store p in place (wave-private row)
        }

        // PV: acc[r][:] += p[r][j] * x[kbase+j][:]   (x float4 loads fully coalesced)
        {
            const float* xbase = x + ((size_t)b * S_ + kbase) * D_;
            #pragma unroll 2
            for (int j = 0; j < TK; ++j) {
                const float4* xr = (const float4*)(xbase + (size_t)j * D_);
                float4 xv0 = xr[lane];
                float4 xv1 = xr[64 + lane];
                float4 xv2 = xr[128 + lane];
                #pragma unroll
                for (int r = 0; r < 8; ++r) {
                    float pv = s_lds[wave * 8 + r][j];
                    FMA4(acc[r][0], pv, xv0);
                    FMA4(acc[r][1], pv, xv1);
                    FMA4(acc[r][2], pv, xv2);
                }
            }
        }
        __syncthreads();   // all waves done with this tile's s/k before next stage
    }

    // epilogue: normalize, apply query mask, write coalesced
    #pragma unroll
    for (int r = 0; r < 8; ++r) {
        const int row = qbase + wave * 8 + r;    // within-batch row
        float mq = mrow[row];
        float inv = (mq > 0.f && l_run[r] > 0.f) ? (1.0f / l_run[r]) : 0.f;
        float* orow = out + ((size_t)b * S_ + row) * D_;
        #pragma unroll
        for (int c = 0; c < 3; ++c) {
            float4 v = acc[r][c];
            v.x *= inv; v.y *= inv; v.z *= inv; v.w *= inv;
            ((float4*)orow)[c * 64 + lane] = v;
        }
    }
}

extern "C" void kernel_launch(void* const* d_in, const int* in_sizes, int n_in,
                              void* d_out, int out_size, void* d_ws, size_t ws_size,
                              hipStream_t stream) {
    const float*         x    = (const float*)d_in[0];
    const unsigned char* mraw = (const unsigned char*)d_in[1];
    const float*         Wq   = (const float*)d_in[2];
    const float*         Wk   = (const float*)d_in[3];
    float*               outp = (float*)d_out;

    // ws layout: maskf [B*S] | q [B*S*U] | k [B*S*U]  (fp32) = ~8.45 MB
    float* maskf = (float*)d_ws;
    float* qb    = maskf + (size_t)B_ * S_;
    float* kb    = qb + (size_t)B_ * S_ * U_;

    decode_mask_k<<<(B_ * S_) / 256, 256, 0, stream>>>(mraw, maskf);
    proj_qk_k<<<(B_ * S_) / 16, 256, 0, stream>>>(x, Wq, Wk, qb, kb);
    attn_k<<<B_ * (S_ / TQ), 256, 0, stream>>>(x, qb, kb, maskf, outp);
}

// Round 2
// 323.419 us; speedup vs baseline: 4.9800x; 4.9800x over previous
//
#include <hip/hip_runtime.h>
#include <math.h>

#define B_ 4
#define S_ 4096
#define D_ 768
#define U_ 64
#define TQ 64
#define TK 32
#define NT (S_ / TK)

typedef __attribute__((ext_vector_type(8))) short short8;
typedef __attribute__((ext_vector_type(4))) float f32x4;
typedef __attribute__((ext_vector_type(16))) float f32x16;

__device__ __forceinline__ unsigned short f2bf(float f) {
    unsigned int x = __float_as_uint(f);
    unsigned int r = (x + 0x7fffu + ((x >> 16) & 1u)) >> 16;
    return (unsigned short)r;
}

#define GLOAD16(gsrc, ldst)                                                             \
    __builtin_amdgcn_global_load_lds(                                                   \
        (const __attribute__((address_space(1))) unsigned int*)(const void*)(gsrc),     \
        (__attribute__((address_space(3))) unsigned int*)(void*)(ldst), 16, 0, 0)

#define BARRIER()                                   \
    {                                               \
        __builtin_amdgcn_sched_barrier(0);          \
        asm volatile("s_barrier" ::: "memory");     \
        __builtin_amdgcn_sched_barrier(0);          \
    }

// ---------------- kernel 1: decode mask (auto-detect bool8 vs int32) ----------------
__global__ __launch_bounds__(256) void decode_mask_k(const unsigned char* __restrict__ mraw,
                                                     float* __restrict__ maskf) {
    int base = threadIdx.x * 4;
    int bad = (mraw[base + 1] | mraw[base + 2] | mraw[base + 3]) != 0;
    int isbyte = __syncthreads_or(bad);
    int i = blockIdx.x * 256 + threadIdx.x;
    if (i < B_ * S_) {
        int v = isbyte ? (int)mraw[i] : ((const int*)mraw)[i];
        maskf[i] = (v != 0) ? 1.0f : 0.0f;
    }
}

// ---------------- kernel 2: q/k projection -> bf16, XOR-swizzled rows ----------------
__global__ __launch_bounds__(256) void proj_qk_k(const float* __restrict__ x,
                                                 const float* __restrict__ Wq,
                                                 const float* __restrict__ Wk,
                                                 unsigned short* __restrict__ qg,
                                                 unsigned short* __restrict__ kg) {
    __shared__ float xs[16][D_];
    const int rbase = blockIdx.x * 16;
    const float4* xsrc = (const float4*)(x + (size_t)rbase * D_);
    float4* xdst = (float4*)&xs[0][0];
    for (int i = threadIdx.x; i < 16 * D_ / 4; i += 256) xdst[i] = xsrc[i];
    __syncthreads();

    const int c  = threadIdx.x & 127;
    const int rg = threadIdx.x >> 7;
    const float* __restrict__ W = (c < 64) ? Wq : Wk;
    const int u = c & 63;

    float acc[8] = {0.f, 0.f, 0.f, 0.f, 0.f, 0.f, 0.f, 0.f};
    #pragma unroll 4
    for (int d = 0; d < D_; ++d) {
        const float wv = W[d * U_ + u];
        #pragma unroll
        for (int r = 0; r < 8; ++r) acc[r] = fmaf(xs[rg * 8 + r][d], wv, acc[r]);
    }
    unsigned short* __restrict__ dst = (c < 64) ? qg : kg;
    #pragma unroll
    for (int r = 0; r < 8; ++r) {
        const int row = rbase + rg * 8 + r;
        const int col = (((u >> 3) ^ (row & 7)) << 3) + (u & 7);
        dst[(size_t)row * U_ + col] = f2bf(acc[r]);
    }
}

// ---------------- kernel 3: transpose x -> xT[b][d][s] bf16, pre-swizzled ----------------
__global__ __launch_bounds__(256) void xpose_k(const float* __restrict__ x,
                                               unsigned short* __restrict__ xTg) {
    __shared__ float xs[64][68];
    const int tid = threadIdx.x;
    int t = blockIdx.x;
    const int dt = t % (D_ / 64); t /= (D_ / 64);
    const int st = t % (S_ / 64); t /= (S_ / 64);
    const int b = t;
    const int s0 = st * 64, d0 = dt * 64;

    #pragma unroll
    for (int it = 0; it < 4; ++it) {
        const int row = (tid >> 4) + it * 16;
        const int ch = tid & 15;
        const float4 v = *(const float4*)&x[(size_t)(b * S_ + s0 + row) * D_ + d0 + ch * 4];
        *(float4*)&xs[row][ch * 4] = v;
    }
    __syncthreads();

    const int d = tid >> 2;
    const int dg = d0 + d;
    #pragma unroll
    for (int half = 0; half < 2; ++half) {
        const int c = (tid & 3) + half * 4;   // s-chunk of 8 within the 64-s tile
        short8 sv;
        #pragma unroll
        for (int e = 0; e < 8; ++e) sv[e] = (short)f2bf(xs[c * 8 + e][d]);
        const int cc = (c & 4) | ((c & 3) ^ (dg & 3));   // swizzle within 32-key window
        unsigned short* dstp = xTg + (size_t)(b * D_ + dg) * S_ + s0 + cc * 8;
        *(short8*)dstp = sv;
    }
}

// ---------------- kernel 4: flash attention, bf16 MFMA ----------------
__global__ __launch_bounds__(512, 2) void attn_k(const unsigned short* __restrict__ xTg,
                                                 const unsigned short* __restrict__ qg,
                                                 const unsigned short* __restrict__ kg,
                                                 const float* __restrict__ maskf,
                                                 float* __restrict__ out) {
    __shared__ __align__(16) unsigned short xT_l[2][D_ * TK];   // 2 x 48KB
    __shared__ __align__(16) unsigned short k_l[2][TK * U_];    // 2 x 4KB
    __shared__ __align__(16) unsigned short q_l[TQ * U_];       // 8KB
    __shared__ __align__(16) unsigned short p_l[TQ * TK];       // 4KB
    __shared__ __align__(16) float mk_l[2][TK];
    __shared__ __align__(16) float scale_l[TQ];
    __shared__ __align__(16) float inv_l[TQ];
    __shared__ int flag_l[4];

    const int tid = threadIdx.x;
    const int w = tid >> 6;
    const int l = tid & 63;
    const int b = blockIdx.x >> 6;
    const int qbase = (blockIdx.x & 63) * TQ;
    const int bS = b * S_;
    const size_t xTbase = (size_t)b * D_ * S_;
    const size_t qkbase = ((size_t)bS + qbase) * U_;

#define STAGE_ALL(buf, kb)                                                                   \
    {                                                                                        \
        _Pragma("unroll")                                                                    \
        for (int i_ = 0; i_ < 6; ++i_) {                                                     \
            const int L_ = i_ * 512 + tid;                                                   \
            const int d_ = L_ >> 2, ch_ = L_ & 3;                                            \
            GLOAD16(xTg + xTbase + (size_t)d_ * S_ + (kb) + ch_ * 8, &xT_l[buf][L_ * 8]);    \
        }                                                                                    \
        if (tid < 256)                                                                       \
            GLOAD16(kg + ((size_t)(bS + (kb) + (tid >> 3))) * U_ + (tid & 7) * 8,            \
                    &k_l[buf][tid * 8]);                                                     \
        if (tid < 8) GLOAD16(maskf + bS + (kb) + tid * 4, &mk_l[buf][tid * 4]);              \
    }

    // ---- prologue staging ----
    GLOAD16(qg + qkbase + tid * 8, &q_l[tid * 8]);
    STAGE_ALL(0, 0);
    asm volatile("s_waitcnt vmcnt(0)" ::: "memory");
    __syncthreads();

    // hoist q fragments (waves 0-3; wave w owns q rows 16w..16w+15)
    short8 qf[2];
    float m_run = -1e30f, l_run = 0.f;
    if (w < 4) {
        const int qq = (w << 4) + (l & 15);
        const int lg = l >> 4;
        #pragma unroll
        for (int h = 0; h < 2; ++h) {
            const int ch = (h << 2) + lg;
            qf[h] = *(const short8*)&q_l[(qq << 6) + ((ch ^ (qq & 7)) << 3)];
        }
    }

    f32x16 acc[2][3];
    {
        f32x16 z = {0.f};
        #pragma unroll
        for (int i = 0; i < 2; ++i)
            #pragma unroll
            for (int j = 0; j < 3; ++j) acc[i][j] = z;
    }

    int cur = 0;
    for (int kt = 0; kt < NT; ++kt) {
        // ---------- phase A: stage next tile (all waves) + QK^T/softmax (waves 0-3) ----------
        if (kt + 1 < NT) {
            const int kb = (kt + 1) * TK;
            STAGE_ALL(cur ^ 1, kb);
        }
        if (w < 4) {
            const int lg = l >> 4;
            const int qloc = (w << 4) + (l & 15);
            f32x4 c0 = {0.f, 0.f, 0.f, 0.f};
            f32x4 c1 = {0.f, 0.f, 0.f, 0.f};
            #pragma unroll
            for (int h = 0; h < 2; ++h) {
                const int ch = (h << 2) + lg;
                const int key0 = l & 15, key1 = 16 + (l & 15);
                const short8 a0 = *(const short8*)&k_l[cur][(key0 << 6) + ((ch ^ (key0 & 7)) << 3)];
                const short8 a1 = *(const short8*)&k_l[cur][(key1 << 6) + ((ch ^ (key1 & 7)) << 3)];
                c0 = __builtin_amdgcn_mfma_f32_16x16x32_bf16(a0, qf[h], c0, 0, 0, 0);
                c1 = __builtin_amdgcn_mfma_f32_16x16x32_bf16(a1, qf[h], c1, 0, 0, 0);
            }
            // mask + scale -> logits (lane holds keys t*16 + lg*4 + r, q = qloc)
            float s[8], mv[8];
            const float4 mk0 = *(const float4*)&mk_l[cur][lg << 2];
            const float4 mk1 = *(const float4*)&mk_l[cur][16 + (lg << 2)];
            mv[0] = mk0.x; mv[1] = mk0.y; mv[2] = mk0.z; mv[3] = mk0.w;
            mv[4] = mk1.x; mv[5] = mk1.y; mv[6] = mk1.z; mv[7] = mk1.w;
            #pragma unroll
            for (int r = 0; r < 4; ++r) {
                s[r]     = (mv[r]     > 0.f) ? c0[r] * 0.125f : -1e30f;
                s[4 + r] = (mv[4 + r] > 0.f) ? c1[r] * 0.125f : -1e30f;
            }
            float mx = s[0];
            #pragma unroll
            for (int r = 1; r < 8; ++r) mx = fmaxf(mx, s[r]);
            mx = fmaxf(mx, __shfl_xor(mx, 16));
            mx = fmaxf(mx, __shfl_xor(mx, 32));
            // defer-max (T13): only rescale when the max grew by > 8
            const bool upd = (mx > m_run + 8.f);
            float sc = 1.f;
            if (upd) { sc = __expf(m_run - mx); m_run = mx; }
            float p[8], ps = 0.f;
            #pragma unroll
            for (int r = 0; r < 8; ++r) { p[r] = mv[r] * __expf(s[r] - m_run); ps += p[r]; }
            ps += __shfl_xor(ps, 16);
            ps += __shfl_xor(ps, 32);
            l_run = l_run * sc + ps;
            if ((l >> 4) == 0) scale_l[qloc] = sc;
            const int fl = __any(upd);
            if (l == 0) flag_l[w] = fl;
            // pack p -> bf16, write swizzled [q][key]
            #pragma unroll
            for (int t = 0; t < 2; ++t) {
                unsigned long long pk =
                      (unsigned long long)f2bf(p[t * 4 + 0])
                    | ((unsigned long long)f2bf(p[t * 4 + 1]) << 16)
                    | ((unsigned long long)f2bf(p[t * 4 + 2]) << 32)
                    | ((unsigned long long)f2bf(p[t * 4 + 3]) << 48);
                const int kb4 = (t << 4) + (lg << 2);
                const int ch8 = kb4 >> 3;
                const int off = (qloc << 5) + ((ch8 ^ (qloc & 3)) << 3) + (kb4 & 7);
                *(unsigned long long*)&p_l[off] = pk;
            }
            asm volatile("s_waitcnt lgkmcnt(0)" ::: "memory");
        }
        BARRIER();   // B1: p/scale/flag published; staged loads stay in flight

        // ---------- phase B: PV (all 8 waves; wave w owns d columns 96w..96w+95) ----------
        const int anyf = flag_l[0] + flag_l[1] + flag_l[2] + flag_l[3];
        if (anyf) {
            #pragma unroll
            for (int i = 0; i < 2; ++i) {
                #pragma unroll
                for (int g = 0; g < 4; ++g) {
                    const float4 sv = *(const float4*)&scale_l[(i << 5) + ((l >> 5) << 2) + (g << 3)];
                    #pragma unroll
                    for (int j = 0; j < 3; ++j) {
                        acc[i][j][(g << 2) + 0] *= sv.x;
                        acc[i][j][(g << 2) + 1] *= sv.y;
                        acc[i][j][(g << 2) + 2] *= sv.z;
                        acc[i][j][(g << 2) + 3] *= sv.w;
                    }
                }
            }
        }
        #pragma unroll
        for (int t = 0; t < 2; ++t) {
            const int ch = (t << 1) + (l >> 5);
            const int q0 = l & 31, q1 = 32 + (l & 31);
            const short8 a0 = *(const short8*)&p_l[(q0 << 5) + ((ch ^ (q0 & 3)) << 3)];
            const short8 a1 = *(const short8*)&p_l[(q1 << 5) + ((ch ^ (q1 & 3)) << 3)];
            #pragma unroll
            for (int j = 0; j < 3; ++j) {
                const int d = w * 96 + (j << 5) + (l & 31);
                const short8 bv = *(const short8*)&xT_l[cur][(d << 5) + ((ch ^ (d & 3)) << 3)];
                acc[0][j] = __builtin_amdgcn_mfma_f32_32x32x16_bf16(a0, bv, acc[0][j], 0, 0, 0);
                acc[1][j] = __builtin_amdgcn_mfma_f32_32x32x16_bf16(a1, bv, acc[1][j], 0, 0, 0);
            }
        }
        __syncthreads();   // B2: drains staged vmcnt; protects p/k/xT reuse
        cur ^= 1;
    }

    // ---------- epilogue: 1/l, query mask, store ----------
    if (w < 4 && (l >> 4) == 0) {
        const int qloc = (w << 4) + l;
        const float mq = maskf[(size_t)bS + qbase + qloc];
        inv_l[qloc] = (mq > 0.f && l_run > 0.f) ? (1.f / l_run) : 0.f;
    }
    __syncthreads();
    #pragma unroll
    for (int i = 0; i < 2; ++i) {
        #pragma unroll
        for (int g = 0; g < 4; ++g) {
            const float4 iv = *(const float4*)&inv_l[(i << 5) + ((l >> 5) << 2) + (g << 3)];
            #pragma unroll
            for (int j = 0; j < 3; ++j) {
                const int dcol = w * 96 + (j << 5) + (l & 31);
                #pragma unroll
                for (int e = 0; e < 4; ++e) {
                    const int row = (i << 5) + ((l >> 5) << 2) + (g << 3) + e;
                    const float ivv = (e == 0) ? iv.x : (e == 1) ? iv.y : (e == 2) ? iv.z : iv.w;
                    out[(size_t)(bS + qbase + row) * D_ + dcol] = acc[i][j][(g << 2) + e] * ivv;
                }
            }
        }
    }
#undef STAGE_ALL
}

extern "C" void kernel_launch(void* const* d_in, const int* in_sizes, int n_in,
                              void* d_out, int out_size, void* d_ws, size_t ws_size,
                              hipStream_t stream) {
    const float*         x    = (const float*)d_in[0];
    const unsigned char* mraw = (const unsigned char*)d_in[1];
    const float*         Wq   = (const float*)d_in[2];
    const float*         Wk   = (const float*)d_in[3];
    float*               outp = (float*)d_out;

    // ws: maskf f32[B*S] | qg bf16[B*S*64] | kg bf16[B*S*64] | xTg bf16[B*768*4096]  (~29.4 MB)
    float* maskf = (float*)d_ws;
    unsigned short* qg  = (unsigned short*)(maskf + (size_t)B_ * S_);
    unsigned short* kg  = qg + (size_t)B_ * S_ * U_;
    unsigned short* xTg = kg + (size_t)B_ * S_ * U_;

    decode_mask_k<<<(B_ * S_) / 256, 256, 0, stream>>>(mraw, maskf);
    proj_qk_k<<<(B_ * S_) / 16, 256, 0, stream>>>(x, Wq, Wk, qg, kg);
    xpose_k<<<B_ * (S_ / 64) * (D_ / 64), 256, 0, stream>>>(x, xTg);
    attn_k<<<B_ * (S_ / TQ), 512, 0, stream>>>(xTg, qg, kg, maskf, outp);
}

// Round 3
// 298.988 us; speedup vs baseline: 5.3869x; 1.0817x over previous
//
#include <hip/hip_runtime.h>
#include <math.h>

#define B_ 4
#define S_ 4096
#define D_ 768
#define U_ 64
#define TQ 64
#define TK 32
#define NT (S_ / TK)
#define XT_TILE (TK * D_)   // 24576 elems (48KB) per key-tile, fragment-ordered
#define K_TILE  (TK * U_)   // 2048 elems (4KB)
#define Q_TILE  (TQ * U_)   // 4096 elems (8KB)

typedef __attribute__((ext_vector_type(8))) short short8;
typedef __attribute__((ext_vector_type(4))) float f32x4;
typedef __attribute__((ext_vector_type(16))) float f32x16;

__device__ __forceinline__ unsigned short f2bf(float f) {
    unsigned int x = __float_as_uint(f);
    unsigned int r = (x + 0x7fffu + ((x >> 16) & 1u)) >> 16;
    return (unsigned short)r;
}

#define GLOAD16(gsrc, ldst)                                                             \
    __builtin_amdgcn_global_load_lds(                                                   \
        (const __attribute__((address_space(1))) unsigned int*)(const void*)(gsrc),     \
        (__attribute__((address_space(3))) unsigned int*)(void*)(ldst), 16, 0, 0)

#define BARRIER()                                   \
    {                                               \
        __builtin_amdgcn_sched_barrier(0);          \
        asm volatile("s_barrier" ::: "memory");     \
        __builtin_amdgcn_sched_barrier(0);          \
    }

// ---------------- kernel 1: decode mask (auto-detect bool8 vs int32) ----------------
__global__ __launch_bounds__(256) void decode_mask_k(const unsigned char* __restrict__ mraw,
                                                     float* __restrict__ maskf) {
    int base = threadIdx.x * 4;
    int bad = (mraw[base + 1] | mraw[base + 2] | mraw[base + 3]) != 0;
    int isbyte = __syncthreads_or(bad);
    int i = blockIdx.x * 256 + threadIdx.x;
    if (i < B_ * S_) {
        int v = isbyte ? (int)mraw[i] : ((const int*)mraw)[i];
        maskf[i] = (v != 0) ? 1.0f : 0.0f;
    }
}

// ---------------- kernel 2: q/k projection -> bf16, MFMA-fragment-ordered ----------------
// qg per 64-row tile: [(w2=row>>4&3)*2+h][lg][col=row&15][e]  (u = h*32+lg*8+e)
// kg per 32-row tile: [h*2+(kb=row>>4&1)][lg][rowf=row&15][e]
__global__ __launch_bounds__(256) void proj_qk_k(const float* __restrict__ x,
                                                 const float* __restrict__ Wq,
                                                 const float* __restrict__ Wk,
                                                 unsigned short* __restrict__ qg,
                                                 unsigned short* __restrict__ kg) {
    __shared__ float xs[16][D_];
    const int rbase = blockIdx.x * 16;
    const float4* xsrc = (const float4*)(x + (size_t)rbase * D_);
    float4* xdst = (float4*)&xs[0][0];
    for (int i = threadIdx.x; i < 16 * D_ / 4; i += 256) xdst[i] = xsrc[i];
    __syncthreads();

    const int c  = threadIdx.x & 127;
    const int rg = threadIdx.x >> 7;
    const float* __restrict__ W = (c < 64) ? Wq : Wk;
    const int u = c & 63;

    float acc[8] = {0.f, 0.f, 0.f, 0.f, 0.f, 0.f, 0.f, 0.f};
    #pragma unroll 4
    for (int d = 0; d < D_; ++d) {
        const float wv = W[d * U_ + u];
        #pragma unroll
        for (int r = 0; r < 8; ++r) acc[r] = fmaf(xs[rg * 8 + r][d], wv, acc[r]);
    }

    const int h  = u >> 5;
    const int lg = (u >> 3) & 3;
    const int e  = u & 7;
    const int row0 = rbase + rg * 8;          // rows row0..row0+7 (same 16-block)
    if (c < 64) {
        unsigned short* dstq = qg + (size_t)(row0 >> 6) * Q_TILE
            + ((((((row0 >> 4) & 3) * 2 + h) * 4 + lg) * 16) + (row0 & 15)) * 8 + e;
        #pragma unroll
        for (int r = 0; r < 8; ++r) dstq[r * 8] = f2bf(acc[r]);
    } else {
        unsigned short* dstk = kg + (size_t)(row0 >> 5) * K_TILE
            + (((h * 2 + ((row0 >> 4) & 1)) * 4 + lg) * 16 + (row0 & 15)) * 8 + e;
        #pragma unroll
        for (int r = 0; r < 8; ++r) dstk[r * 8] = f2bf(acc[r]);
    }
}

// ---------------- kernel 3: x -> xT B-fragments, per (b, key-tile) ----------------
// xTg per key-tile: chunk c in [0,3072): kw=c/1536, db=(c>>6)%24, kh=(c>>5)&1, col=c&31
// chunk holds x[s = kt*32 + kw*16 + kh*8 + e][d = db*32 + col], e=0..7 (bf16)
__global__ __launch_bounds__(512) void xpose_k(const float* __restrict__ x,
                                               unsigned short* __restrict__ xTg) {
    __shared__ float xs[TK][D_ + 4];   // +4 pad: column reads spread banks
    const int tid = threadIdx.x;
    const int bt  = blockIdx.x;             // b*128 + kt
    const int s0  = (bt & 127) * TK;
    const int b   = bt >> 7;
    const float* xsrc = x + ((size_t)(b * S_ + s0)) * D_;
    const int r_ = tid >> 4, c_ = tid & 15;
    #pragma unroll
    for (int it = 0; it < 12; ++it) {
        const int col4 = c_ + it * 16;
        *(float4*)&xs[r_][col4 * 4] = *(const float4*)&xsrc[(size_t)r_ * D_ + col4 * 4];
    }
    __syncthreads();

    unsigned short* dst = xTg + (size_t)bt * XT_TILE;
    #pragma unroll
    for (int it = 0; it < 6; ++it) {
        const int cch = it * 512 + tid;
        const int col = cch & 31;
        const int kh  = (cch >> 5) & 1;
        const int db  = (cch >> 6) % 24;
        const int kw  = (cch >> 6) / 24;
        const int d   = db * 32 + col;
        const int sr  = kw * 16 + kh * 8;
        short8 v;
        #pragma unroll
        for (int e = 0; e < 8; ++e) v[e] = (short)f2bf(xs[sr + e][d]);
        *(short8*)&dst[cch * 8] = v;
    }
}

// ---------------- kernel 4: flash attention, bf16 MFMA, conflict-free LDS ----------------
__global__ __launch_bounds__(512, 2) void attn_k(const unsigned short* __restrict__ xTg,
                                                 const unsigned short* __restrict__ qg,
                                                 const unsigned short* __restrict__ kg,
                                                 const float* __restrict__ maskf,
                                                 float* __restrict__ out) {
    __shared__ __align__(16) unsigned short xT_l[2][XT_TILE];   // 2 x 48KB
    __shared__ __align__(16) unsigned short k_l[2][K_TILE];     // 2 x 4KB
    __shared__ __align__(16) unsigned short q_l[Q_TILE];        // 8KB
    __shared__ __align__(16) unsigned short p_l[TQ * TK];       // 4KB
    __shared__ __align__(16) float mk_l[2][TK];
    __shared__ __align__(16) float scale_l[TQ];
    __shared__ __align__(16) float inv_l[TQ];
    __shared__ int flag_l[4];

    const int tid = threadIdx.x;
    const int w = tid >> 6;
    const int l = tid & 63;
    const int lg = l >> 4;
    const int b = blockIdx.x >> 6;
    const int qbase = (blockIdx.x & 63) * TQ;
    const int bS = b * S_;
    const unsigned short* xT_t = xTg + (size_t)b * NT * XT_TILE;
    const unsigned short* kg_t = kg + (size_t)b * NT * K_TILE;
    const float* mk_g = maskf + bS;

#define STAGE_ALL(buf, ktile)                                                        \
    {                                                                                \
        const unsigned short* xs_ = xT_t + (size_t)(ktile) * XT_TILE;                \
        _Pragma("unroll")                                                            \
        for (int i_ = 0; i_ < 6; ++i_)                                               \
            GLOAD16(xs_ + (i_ * 512 + tid) * 8, &xT_l[buf][(i_ * 512 + tid) * 8]);   \
        if (tid < 256)                                                               \
            GLOAD16(kg_t + (size_t)(ktile) * K_TILE + tid * 8, &k_l[buf][tid * 8]);  \
        if (tid < 8) GLOAD16(mk_g + (ktile) * TK + tid * 4, &mk_l[buf][tid * 4]);    \
    }

    // ---- prologue staging ----
    GLOAD16(qg + (size_t)blockIdx.x * Q_TILE + tid * 8, &q_l[tid * 8]);
    STAGE_ALL(0, 0);
    asm volatile("s_waitcnt vmcnt(0)" ::: "memory");
    __syncthreads();

    short8 qf[2];
    float m_run = -1e30f, l_run = 0.f;
    if (w < 4) {
        #pragma unroll
        for (int h = 0; h < 2; ++h)
            qf[h] = *(const short8*)&q_l[(((w * 2 + h) * 4 + lg) * 16 + (l & 15)) * 8];
    }

    f32x16 acc[2][3];
    {
        f32x16 z = {0.f};
        #pragma unroll
        for (int i = 0; i < 2; ++i)
            #pragma unroll
            for (int j = 0; j < 3; ++j) acc[i][j] = z;
    }

    int cur = 0;
    for (int kt = 0; kt < NT; ++kt) {
        // ---------- phase A: stage next tile (all waves) + QK^T/softmax (waves 0-3) ----------
        if (kt + 1 < NT) STAGE_ALL(cur ^ 1, kt + 1);
        if (w < 4) {
            const int qloc = (w << 4) + (l & 15);
            f32x4 c0 = {0.f, 0.f, 0.f, 0.f};
            f32x4 c1 = {0.f, 0.f, 0.f, 0.f};
            #pragma unroll
            for (int h = 0; h < 2; ++h) {
                const short8 a0 = *(const short8*)&k_l[cur][(((h * 2 + 0) * 4 + lg) * 16 + (l & 15)) * 8];
                const short8 a1 = *(const short8*)&k_l[cur][(((h * 2 + 1) * 4 + lg) * 16 + (l & 15)) * 8];
                c0 = __builtin_amdgcn_mfma_f32_16x16x32_bf16(a0, qf[h], c0, 0, 0, 0);
                c1 = __builtin_amdgcn_mfma_f32_16x16x32_bf16(a1, qf[h], c1, 0, 0, 0);
            }
            // lane holds: c0[r] = S[key=lg*4+r][qloc], c1[r] = S[key=16+lg*4+r][qloc]
            float s[8], mv[8];
            const float4 mk0 = *(const float4*)&mk_l[cur][lg << 2];
            const float4 mk1 = *(const float4*)&mk_l[cur][16 + (lg << 2)];
            mv[0] = mk0.x; mv[1] = mk0.y; mv[2] = mk0.z; mv[3] = mk0.w;
            mv[4] = mk1.x; mv[5] = mk1.y; mv[6] = mk1.z; mv[7] = mk1.w;
            #pragma unroll
            for (int r = 0; r < 4; ++r) {
                s[r]     = (mv[r]     > 0.f) ? c0[r] * 0.125f : -1e30f;
                s[4 + r] = (mv[4 + r] > 0.f) ? c1[r] * 0.125f : -1e30f;
            }
            float mx = s[0];
            #pragma unroll
            for (int r = 1; r < 8; ++r) mx = fmaxf(mx, s[r]);
            mx = fmaxf(mx, __shfl_xor(mx, 16));
            mx = fmaxf(mx, __shfl_xor(mx, 32));
            const bool upd = (mx > m_run + 8.f);   // defer-max (T13)
            float sc = 1.f;
            if (upd) { sc = __expf(m_run - mx); m_run = mx; }
            float p[8], ps = 0.f;
            #pragma unroll
            for (int r = 0; r < 8; ++r) { p[r] = mv[r] * __expf(s[r] - m_run); ps += p[r]; }
            ps += __shfl_xor(ps, 16);
            ps += __shfl_xor(ps, 32);
            l_run = l_run * sc + ps;
            if (lg == 0) scale_l[qloc] = sc;
            const int fl = __any(upd);
            if (l == 0) flag_l[w] = fl;
            // pack p -> bf16 A-fragments: chunk = ((kw*2+qh)*2+kh)*32+qr, 8B at e-base (lg&1)*4
            const int qh = qloc >> 5, qr = qloc & 31;
            const int kh = lg >> 1, eb = (lg & 1) << 2;
            #pragma unroll
            for (int t = 0; t < 2; ++t) {
                unsigned long long pk =
                      (unsigned long long)f2bf(p[t * 4 + 0])
                    | ((unsigned long long)f2bf(p[t * 4 + 1]) << 16)
                    | ((unsigned long long)f2bf(p[t * 4 + 2]) << 32)
                    | ((unsigned long long)f2bf(p[t * 4 + 3]) << 48);
                const int chunk = ((t * 2 + qh) * 2 + kh) * 32 + qr;
                *(unsigned long long*)&p_l[chunk * 8 + eb] = pk;
            }
            asm volatile("s_waitcnt lgkmcnt(0)" ::: "memory");
        }
        BARRIER();   // B1: p/scale/flag published; staged loads stay in flight

        // ---------- phase B: PV (all 8 waves; wave w owns d columns 96w..96w+95) ----------
        const int anyf = flag_l[0] + flag_l[1] + flag_l[2] + flag_l[3];
        if (anyf) {
            #pragma unroll
            for (int i = 0; i < 2; ++i) {
                #pragma unroll
                for (int g = 0; g < 4; ++g) {
                    const float4 sv = *(const float4*)&scale_l[(i << 5) + ((l >> 5) << 2) + (g << 3)];
                    #pragma unroll
                    for (int j = 0; j < 3; ++j) {
                        acc[i][j][(g << 2) + 0] *= sv.x;
                        acc[i][j][(g << 2) + 1] *= sv.y;
                        acc[i][j][(g << 2) + 2] *= sv.z;
                        acc[i][j][(g << 2) + 3] *= sv.w;
                    }
                }
            }
        }
        {
            const int khp = l >> 5;
            #pragma unroll
            for (int t = 0; t < 2; ++t) {
                const short8 a0 = *(const short8*)&p_l[(((t * 2 + 0) * 2 + khp) * 32 + (l & 31)) * 8];
                const short8 a1 = *(const short8*)&p_l[(((t * 2 + 1) * 2 + khp) * 32 + (l & 31)) * 8];
                #pragma unroll
                for (int j = 0; j < 3; ++j) {
                    const int db = w * 3 + j;
                    const short8 bv = *(const short8*)&xT_l[cur][(((t * 24 + db) * 2 + khp) * 32 + (l & 31)) * 8];
                    acc[0][j] = __builtin_amdgcn_mfma_f32_32x32x16_bf16(a0, bv, acc[0][j], 0, 0, 0);
                    acc[1][j] = __builtin_amdgcn_mfma_f32_32x32x16_bf16(a1, bv, acc[1][j], 0, 0, 0);
                }
            }
        }
        __syncthreads();   // B2: drains staged vmcnt; protects p/k/xT reuse
        cur ^= 1;
    }

    // ---------- epilogue: 1/l, query mask, store ----------
    if (w < 4 && lg == 0) {
        const int qloc = (w << 4) + (l & 15);
        const float mq = maskf[(size_t)bS + qbase + qloc];
        inv_l[qloc] = (mq > 0.f && l_run > 0.f) ? (1.f / l_run) : 0.f;
    }
    __syncthreads();
    #pragma unroll
    for (int i = 0; i < 2; ++i) {
        #pragma unroll
        for (int g = 0; g < 4; ++g) {
            const float4 iv = *(const float4*)&inv_l[(i << 5) + ((l >> 5) << 2) + (g << 3)];
            #pragma unroll
            for (int j = 0; j < 3; ++j) {
                const int dcol = w * 96 + (j << 5) + (l & 31);
                #pragma unroll
                for (int e = 0; e < 4; ++e) {
                    const int row = (i << 5) + ((l >> 5) << 2) + (g << 3) + e;
                    const float ivv = (e == 0) ? iv.x : (e == 1) ? iv.y : (e == 2) ? iv.z : iv.w;
                    out[(size_t)(bS + qbase + row) * D_ + dcol] = acc[i][j][(g << 2) + e] * ivv;
                }
            }
        }
    }
#undef STAGE_ALL
}

extern "C" void kernel_launch(void* const* d_in, const int* in_sizes, int n_in,
                              void* d_out, int out_size, void* d_ws, size_t ws_size,
                              hipStream_t stream) {
    const float*         x    = (const float*)d_in[0];
    const unsigned char* mraw = (const unsigned char*)d_in[1];
    const float*         Wq   = (const float*)d_in[2];
    const float*         Wk   = (const float*)d_in[3];
    float*               outp = (float*)d_out;

    // ws: maskf f32[B*S] | qg bf16[B*S*64] | kg bf16[B*S*64] | xTg bf16[B*768*4096]
    float* maskf = (float*)d_ws;
    unsigned short* qg  = (unsigned short*)(maskf + (size_t)B_ * S_);
    unsigned short* kg  = qg + (size_t)B_ * S_ * U_;
    unsigned short* xTg = kg + (size_t)B_ * S_ * U_;

    decode_mask_k<<<(B_ * S_) / 256, 256, 0, stream>>>(mraw, maskf);
    proj_qk_k<<<(B_ * S_) / 16, 256, 0, stream>>>(x, Wq, Wk, qg, kg);
    xpose_k<<<B_ * (S_ / TK), 512, 0, stream>>>(x, xTg);
    attn_k<<<B_ * (S_ / TQ), 512, 0, stream>>>(xTg, qg, kg, maskf, outp);
}